// Round 3
// baseline (25933.740 us; speedup 1.0000x reference)
//
#include <hip/hip_runtime.h>

typedef unsigned short u16;
typedef unsigned int   u32;
typedef _Float16 v8hf __attribute__((ext_vector_type(8)));
typedef float  f32x4 __attribute__((ext_vector_type(4)));

// ---------------- problem constants ----------------
static constexpr int B_   = 2048;
static constexpr int T_   = 64;
static constexpr int D_   = 64;
static constexpr int H_   = 256;
static constexpr int NL_  = 10;
static constexpr int FUT_ = 96;
static constexpr int NBLK = 128;     // B/16

// workspace layout (bytes)
static constexpr size_t WF_LAYER_ELEMS = 524288;          // u16 per layer (1 MiB)
static constexpr size_t SEQ_OFF        = 16u << 20;       // seq buffer at +16 MiB
// seq: fp16 [NBLK][T][16][256]  = 64 MiB

// ---------------- small helpers ----------------
__device__ __forceinline__ u16 f2h(float f) {
  _Float16 h = (_Float16)f;                 // RNE v_cvt_f16_f32
  return __builtin_bit_cast(u16, h);
}
__device__ __forceinline__ float h2f(u16 b) {
  return (float)__builtin_bit_cast(_Float16, b);
}
__device__ __forceinline__ float rcp_(float x) { return __builtin_amdgcn_rcpf(x); }
__device__ __forceinline__ float fsig(float x) { return rcp_(1.f + __expf(-x)); }
__device__ __forceinline__ float ftanh(float x) {
  float e = __expf(-2.f * fabsf(x));
  float t = (1.f - e) * rcp_(1.f + e);
  return copysignf(t, x);
}

// ---------------- weight packing (fp16 B-fragment order) ----------------
// Fragment (gnt, kc): element (lane, i) = Wcat[g = gnt*16 + (lane&15)][k = kc*32 + (lane>>4)*8 + i]
__global__ void pack_weights_v3(const float* __restrict__ Wih0,
                                const float* __restrict__ Wih,
                                const float* __restrict__ Whh,
                                u16* __restrict__ wf) {
  int gid = blockIdx.x * 256 + threadIdx.x;
  int l   = gid >> 16;            // 65536 frag-threads per layer
  if (l >= NL_) return;
  int rem  = gid & 65535;
  int gnt  = rem >> 10;           // 0..63
  int kc   = (rem >> 6) & 15;     // 0..15
  int lane = rem & 63;
  const int NKC = (l == 0) ? 10 : 16;
  if (kc >= NKC) return;
  const int KX = (l == 0) ? 64 : 256;

  int g  = gnt * 16 + (lane & 15);
  int k0 = kc * 32 + (lane >> 4) * 8;

  float v[8];
#pragma unroll
  for (int i = 0; i < 8; ++i) {
    int k = k0 + i;
    float x;
    if (l == 0) x = (k < KX) ? Wih0[g * 64 + k] : Whh[g * 256 + (k - KX)];
    else        x = (k < KX) ? Wih[(size_t)((l - 1) * 1024 + g) * 256 + k]
                             : Whh[(size_t)(l * 1024 + g) * 256 + (k - KX)];
    v[i] = x;
  }
  u32 pk[4];
#pragma unroll
  for (int i = 0; i < 4; ++i)
    pk[i] = (u32)f2h(v[2 * i]) | ((u32)f2h(v[2 * i + 1]) << 16);
  uint4 val; val.x = pk[0]; val.y = pk[1]; val.z = pk[2]; val.w = pk[3];
  u16* dst = wf + (size_t)l * WF_LAYER_ELEMS + ((size_t)(gnt * NKC + kc) * 64 + lane) * 8;
  *(uint4*)dst = val;
}

// ---------------- LSTM layer (split-fp16 A: a = a_hi + a_lo) ----------------
// One block = 16 batch rows, 4 waves = 4 gates. A (hi & lo) 16 x K fp16 in LDS,
// row stride 1024B, XOR swizzle (row&7)<<4. W fragments streamed from L2,
// each fragment used for both hi and lo MFMA (no extra streaming).
// KCLO0: first kc with nonzero lo (0 for L0 since X is f32; 8 otherwise —
// x-part comes from fp16 seq, so its lo is exactly 0 and is skipped).
template <int NKC, int KX, int KCLO0, bool L0>
__global__ __launch_bounds__(256, 1) void lstm_layer_v3(
    const float* __restrict__ X,      // only for L0
    u16* __restrict__ seq,            // [NBLK][T][16][256] fp16, in-place x->h
    const u16* __restrict__ wf,       // this layer's packed weights
    const float* __restrict__ bias)   // [1024]
{
  __shared__ __align__(16) u16  Ahi[16 * 512];        // 16 KiB
  __shared__ __align__(16) u16  Alo[16 * 512];        // 16 KiB
  __shared__ float glds[4][16][260];                  // 65 KiB

  const int tid  = threadIdx.x;
  const int w    = tid >> 6;
  const int lane = tid & 63;
  const int bid  = blockIdx.x;
  const int arow = lane & 15;          // A row / D col within MFMA
  const int ahi  = lane >> 4;          // k-group / D row-group
  const int aswz = (arow & 7) << 4;

  // zero h-part of Ahi (512B/row from byte KX*2) and ALL of Alo.
  // zeros are swizzle-agnostic (XOR permutes 16B blocks within the region).
  {
    int r = tid >> 4, o = (tid & 15) * 32;
    uint4 z; z.x = z.y = z.z = z.w = 0;
    char* p = (char*)Ahi + r * 1024 + KX * 2 + o;
    *(uint4*)p = z; *(uint4*)(p + 16) = z;
    int o2 = (tid & 15) * 64;
    char* q = (char*)Alo + r * 1024 + o2;
    *(uint4*)q = z; *(uint4*)(q + 16) = z; *(uint4*)(q + 32) = z; *(uint4*)(q + 48) = z;
  }

  float c[16];
#pragma unroll
  for (int r = 0; r < 16; ++r) c[r] = 0.f;

  float bv[16];
#pragma unroll
  for (int nt = 0; nt < 16; ++nt) bv[nt] = bias[w * 256 + nt * 16 + arow];

  const u16* wbase = wf + (size_t)(w * 16 * NKC) * 512 + lane * 8;

  for (int t = 0; t < T_; ++t) {
    // ---- phase 1: load x_t into A (swizzled) ----
    if constexpr (L0) {
      int r = tid >> 4, seg = tid & 15;
      const float4 xv = *(const float4*)(X + ((size_t)(bid * 16 + r) * T_ + t) * D_ + seg * 4);
      u16 h0 = f2h(xv.x), h1 = f2h(xv.y), h2 = f2h(xv.z), h3 = f2h(xv.w);
      uint2 hi, lo;
      hi.x = (u32)h0 | ((u32)h1 << 16);
      hi.y = (u32)h2 | ((u32)h3 << 16);
      lo.x = (u32)f2h(xv.x - h2f(h0)) | ((u32)f2h(xv.y - h2f(h1)) << 16);
      lo.y = (u32)f2h(xv.z - h2f(h2)) | ((u32)f2h(xv.w - h2f(h3)) << 16);
      int off = r * 1024 + ((seg * 8) ^ ((r & 7) << 4));
      *(uint2*)((char*)Ahi + off) = hi;
      *(uint2*)((char*)Alo + off) = lo;
    } else {
#pragma unroll
      for (int cc = 0; cc < 2; ++cc) {
        int ch = tid + cc * 256;
        int r = ch >> 5, seg = ch & 31;
        uint4 v = *(const uint4*)(seq + ((((size_t)bid * T_ + t) * 16 + r) << 8) + seg * 8);
        *(uint4*)((char*)Ahi + r * 1024 + ((seg * 16) ^ ((r & 7) << 4))) = v;
        // x-part of Alo stays zero (seq is exactly fp16) and is skipped via KCLO0
      }
    }
    __syncthreads();

    // ---- phase 2: gates = (Ahi+Alo) @ Wcat^T + b  (MFMA 16x16x32 f16) ----
    v8hf a[NKC];
    v8hf al[NKC - KCLO0];
#pragma unroll
    for (int kc = 0; kc < NKC; ++kc)
      a[kc] = *(const v8hf*)((const char*)Ahi + arow * 1024 + ((kc * 64 + ahi * 16) ^ aswz));
#pragma unroll
    for (int kc = KCLO0; kc < NKC; ++kc)
      al[kc - KCLO0] = *(const v8hf*)((const char*)Alo + arow * 1024 + ((kc * 64 + ahi * 16) ^ aswz));

#pragma unroll
    for (int nt = 0; nt < 16; ++nt) {
      f32x4 acc = {bv[nt], bv[nt], bv[nt], bv[nt]};
      const u16* wp = wbase + (size_t)(nt * NKC) * 512;
#pragma unroll
      for (int kc = 0; kc < NKC; ++kc) {
        v8hf bfrag = *(const v8hf*)(const void*)(wp + kc * 512);
        acc = __builtin_amdgcn_mfma_f32_16x16x32_f16(a[kc], bfrag, acc, 0, 0, 0);
        if (kc >= KCLO0)
          acc = __builtin_amdgcn_mfma_f32_16x16x32_f16(al[kc - KCLO0], bfrag, acc, 0, 0, 0);
      }
#pragma unroll
      for (int q = 0; q < 4; ++q)
        glds[w][ahi * 4 + q][nt * 16 + arow] = acc[q];   // D: row=(lane>>4)*4+q, col=lane&15
    }
    __syncthreads();

    // ---- phase 3: nonlinearity + state update; thread owns column j = tid ----
    const int j = tid;
    u16* srow = seq + ((((size_t)bid * T_ + t) * 16) << 8) + j;
#pragma unroll
    for (int r = 0; r < 16; ++r) {
      float iv = glds[0][r][j], fv = glds[1][r][j];
      float gv = glds[2][r][j], ov = glds[3][r][j];
      float cn = fsig(fv) * c[r] + fsig(iv) * ftanh(gv);
      c[r] = cn;
      float h = fsig(ov) * ftanh(cn);
      u16 hb = f2h(h);
      u16 hl = f2h(h - h2f(hb));
      srow[r << 8] = hb;                                 // global (next layer / tail)
      int hoff = r * 1024 + (((KX + j) * 2) ^ ((r & 7) << 4));
      *(u16*)((char*)Ahi + hoff) = hb;
      *(u16*)((char*)Alo + hoff) = hl;
    }
    // next phase-1 writes a disjoint A region; barrier before phase 2 orders all.
  }
}

// ---------------- tail (encoder / sample / decoder) ----------------
template <int N, int K, bool RELU>
__device__ __forceinline__ void dense(const float (*__restrict__ in)[512],
                                      float (*__restrict__ out)[512],
                                      const float* __restrict__ W,
                                      const float* __restrict__ bg, int tid) {
  for (int e = tid; e < 16 * N; e += 256) {
    int r = e / N, n = e - r * N;
    const float* wr = W + (size_t)n * K;
    const float* ar = in[r];
    float4 acc = {0.f, 0.f, 0.f, 0.f};
    for (int k = 0; k < K; k += 4) {
      float4 wv = *(const float4*)(wr + k);
      float4 av = *(const float4*)(ar + k);
      acc.x = fmaf(wv.x, av.x, acc.x);
      acc.y = fmaf(wv.y, av.y, acc.y);
      acc.z = fmaf(wv.z, av.z, acc.z);
      acc.w = fmaf(wv.w, av.w, acc.w);
    }
    float s = bg[n] + acc.x + acc.y + acc.z + acc.w;
    out[r][n] = RELU ? fmaxf(s, 0.f) : s;
  }
}

template <int K>
__device__ __forceinline__ float dotK(const float* __restrict__ a, const float* __restrict__ w) {
  float4 acc = {0.f, 0.f, 0.f, 0.f};
#pragma unroll
  for (int k = 0; k < K; k += 4) {
    float4 wv = *(const float4*)(w + k);
    float4 av = *(const float4*)(a + k);
    acc.x = fmaf(wv.x, av.x, acc.x);
    acc.y = fmaf(wv.y, av.y, acc.y);
    acc.z = fmaf(wv.z, av.z, acc.z);
    acc.w = fmaf(wv.w, av.w, acc.w);
  }
  return acc.x + acc.y + acc.z + acc.w;
}

struct TailArgs {
  const u16* seq;
  const float *ef1w, *ef1b, *ef2w, *ef2b;
  const float *mean_w, *mean_b, *logvar_w, *logvar_b;
  const float *scale_w, *scale_b, *shape_w, *shape_b;
  const float *df1w, *df1b, *df2w, *df2b, *outw, *outb, *finw, *finb;
  const float *pi, *eps, *u, *choice;
  float* out;
};

__global__ __launch_bounds__(256) void tail_kernel_v3(TailArgs A) {
  __shared__ float a0[16][512];
  __shared__ float a1[16][512];
  const int tid = threadIdx.x, bid = blockIdx.x;

  // last hidden state (t = T-1) of final layer
  for (int e = tid; e < 16 * 256; e += 256) {
    int r = e >> 8, jj = e & 255;
    a0[r][jj] = h2f(A.seq[((((size_t)bid * T_ + (T_ - 1)) * 16 + r) << 8) + jj]);
  }
  __syncthreads();

  dense<128, 256, true>(a0, a1, A.ef1w, A.ef1b, tid); __syncthreads();
  dense<64, 128, true>(a1, a0, A.ef2w, A.ef2b, tid);  __syncthreads();

  // heads + reparameterization / GPD mixture
  const float pi = *A.pi;
  for (int e = tid; e < 16 * 64; e += 256) {
    int r = e >> 6, n = e & 63;
    size_t rg = (size_t)bid * 16 + r;
    float m  = dotK<64>(a0[r], A.mean_w   + n * 64) + A.mean_b[n];
    float lv = dotK<64>(a0[r], A.logvar_w + n * 64) + A.logvar_b[n];
    float sc = __expf(dotK<64>(a0[r], A.scale_w + n * 64) + A.scale_b[n]);
    float sh = dotK<64>(a0[r], A.shape_w + n * 64) + A.shape_b[n];
    A.out[196608 + rg * 64 + n] = m;    // z_mean
    A.out[327680 + rg * 64 + n] = lv;   // z_logvar
    A.out[458752 + rg * 64 + n] = sc;   // z_scale
    A.out[589824 + rg * 64 + n] = sh;   // z_shape
    float zg = m + A.eps[rg * 64 + n] * __expf(0.5f * lv);
    float L  = log1pf(-A.u[rg * 64 + n]);
    float zp = sc / sh * (__expf(-sh * L) - 1.f);
    a1[r][n] = (A.choice[rg] < pi) ? zg : zp;
  }
  __syncthreads();

  dense<128, 64, true>(a1, a0, A.df1w, A.df1b, tid);   __syncthreads();
  dense<500, 128, true>(a0, a1, A.df2w, A.df2b, tid);  __syncthreads();
  dense<96, 500, false>(a1, a0, A.outw, A.outb, tid);  __syncthreads();
  dense<96, 96, false>(a0, a1, A.finw, A.finb, tid);   __syncthreads();

  for (int e = tid; e < 16 * FUT_; e += 256) {
    int r = e / FUT_, n = e - r * FUT_;
    A.out[((size_t)bid * 16 + r) * FUT_ + n] = a1[r][n];
  }
}

// ---------------- launch ----------------
extern "C" void kernel_launch(void* const* d_in, const int* in_sizes, int n_in,
                              void* d_out, int out_size, void* d_ws, size_t ws_size,
                              hipStream_t stream) {
  (void)in_sizes; (void)n_in; (void)out_size; (void)ws_size;

  const float* X      = (const float*)d_in[0];
  const float* Wih0   = (const float*)d_in[1];
  const float* Wih    = (const float*)d_in[2];
  const float* Whh    = (const float*)d_in[3];
  const float* b      = (const float*)d_in[4];
  const float* ef1w   = (const float*)d_in[5];
  const float* ef1b   = (const float*)d_in[6];
  const float* ef2w   = (const float*)d_in[7];
  const float* ef2b   = (const float*)d_in[8];
  const float* mean_w = (const float*)d_in[9];
  const float* mean_b = (const float*)d_in[10];
  const float* logvar_w = (const float*)d_in[11];
  const float* logvar_b = (const float*)d_in[12];
  const float* scale_w  = (const float*)d_in[13];
  const float* scale_b  = (const float*)d_in[14];
  const float* shape_w  = (const float*)d_in[15];
  const float* shape_b  = (const float*)d_in[16];
  const float* df1w   = (const float*)d_in[17];
  const float* df1b   = (const float*)d_in[18];
  const float* df2w   = (const float*)d_in[19];
  const float* df2b   = (const float*)d_in[20];
  const float* outw   = (const float*)d_in[21];
  const float* outb   = (const float*)d_in[22];
  const float* finw   = (const float*)d_in[23];
  const float* finb   = (const float*)d_in[24];
  const float* pi_g   = (const float*)d_in[25];
  const float* eps    = (const float*)d_in[26];
  const float* u      = (const float*)d_in[27];
  const float* choice = (const float*)d_in[28];

  u16* wf  = (u16*)d_ws;
  u16* seq = (u16*)((char*)d_ws + SEQ_OFF);
  float* out = (float*)d_out;

  pack_weights_v3<<<2560, 256, 0, stream>>>(Wih0, Wih, Whh, wf);

  // LSTM stack (in-place on seq; layer 0 reads X)
  lstm_layer_v3<10, 64, 0, true><<<NBLK, 256, 0, stream>>>(X, seq, wf, b);
  for (int l = 1; l < NL_; ++l)
    lstm_layer_v3<16, 256, 8, false><<<NBLK, 256, 0, stream>>>(nullptr, seq,
        wf + (size_t)l * WF_LAYER_ELEMS, b + l * 1024);

  TailArgs A;
  A.seq = seq;
  A.ef1w = ef1w; A.ef1b = ef1b; A.ef2w = ef2w; A.ef2b = ef2b;
  A.mean_w = mean_w; A.mean_b = mean_b; A.logvar_w = logvar_w; A.logvar_b = logvar_b;
  A.scale_w = scale_w; A.scale_b = scale_b; A.shape_w = shape_w; A.shape_b = shape_b;
  A.df1w = df1w; A.df1b = df1b; A.df2w = df2w; A.df2b = df2b;
  A.outw = outw; A.outb = outb; A.finw = finw; A.finb = finb;
  A.pi = pi_g; A.eps = eps; A.u = u; A.choice = choice;
  A.out = out;
  tail_kernel_v3<<<NBLK, 256, 0, stream>>>(A);
}

// Round 4
// 23816.771 us; speedup vs baseline: 1.0889x; 1.0889x over previous
//
#include <hip/hip_runtime.h>

typedef unsigned short u16;
typedef unsigned int   u32;
typedef _Float16 v8hf __attribute__((ext_vector_type(8)));
typedef float  f32x4 __attribute__((ext_vector_type(4)));

// ---------------- problem constants ----------------
static constexpr int B_   = 2048;
static constexpr int T_   = 64;
static constexpr int D_   = 64;
static constexpr int H_   = 256;
static constexpr int NL_  = 10;
static constexpr int FUT_ = 96;
static constexpr int NBLK = 128;     // B/16

// workspace layout (bytes)
static constexpr size_t WF_LAYER_ELEMS = 524288;          // u16 per layer (1 MiB)
static constexpr size_t SEQ_OFF        = 16u << 20;       // seq buffer at +16 MiB
// seq: fp16 [NBLK][T][16][256]  = 64 MiB

// ---------------- small helpers ----------------
__device__ __forceinline__ u16 f2h(float f) {
  _Float16 h = (_Float16)f;                 // RNE v_cvt_f16_f32
  return __builtin_bit_cast(u16, h);
}
__device__ __forceinline__ float h2f(u16 b) {
  return (float)__builtin_bit_cast(_Float16, b);
}
__device__ __forceinline__ float rcp_(float x) { return __builtin_amdgcn_rcpf(x); }
__device__ __forceinline__ float fsig(float x) { return rcp_(1.f + __expf(-x)); }
__device__ __forceinline__ float ftanh(float x) {
  float e = __expf(-2.f * fabsf(x));
  float t = (1.f - e) * rcp_(1.f + e);
  return copysignf(t, x);
}

// ---------------- weight packing (fp16 B-fragment order) ----------------
// Fragment (gnt, kc): element (lane, i) = Wcat[g = gnt*16 + (lane&15)][k = kc*32 + (lane>>4)*8 + i]
__global__ void pack_weights_v4(const float* __restrict__ Wih0,
                                const float* __restrict__ Wih,
                                const float* __restrict__ Whh,
                                u16* __restrict__ wf) {
  int gid = blockIdx.x * 256 + threadIdx.x;
  int l   = gid >> 16;            // 65536 frag-threads per layer
  if (l >= NL_) return;
  int rem  = gid & 65535;
  int gnt  = rem >> 10;           // 0..63
  int kc   = (rem >> 6) & 15;     // 0..15
  int lane = rem & 63;
  const int NKC = (l == 0) ? 10 : 16;
  if (kc >= NKC) return;
  const int KX = (l == 0) ? 64 : 256;

  int g  = gnt * 16 + (lane & 15);
  int k0 = kc * 32 + (lane >> 4) * 8;

  float v[8];
#pragma unroll
  for (int i = 0; i < 8; ++i) {
    int k = k0 + i;
    float x;
    if (l == 0) x = (k < KX) ? Wih0[g * 64 + k] : Whh[g * 256 + (k - KX)];
    else        x = (k < KX) ? Wih[(size_t)((l - 1) * 1024 + g) * 256 + k]
                             : Whh[(size_t)(l * 1024 + g) * 256 + (k - KX)];
    v[i] = x;
  }
  u32 pk[4];
#pragma unroll
  for (int i = 0; i < 4; ++i)
    pk[i] = (u32)f2h(v[2 * i]) | ((u32)f2h(v[2 * i + 1]) << 16);
  uint4 val; val.x = pk[0]; val.y = pk[1]; val.z = pk[2]; val.w = pk[3];
  u16* dst = wf + (size_t)l * WF_LAYER_ELEMS + ((size_t)(gnt * NKC + kc) * 64 + lane) * 8;
  *(uint4*)dst = val;
}

// ---------------- LSTM layer v4 ----------------
// One block = 16 batch rows, 512 threads = 8 waves = 4 gates x 2 K-halves.
// Wave (w, kh): gate w (cols w*256..), kc in [kh*KCL, (kh+1)*KCL).
// A = [x_t ; h_{t-1}] 16 x K fp16 in LDS (row stride 1024B fixed, XOR swizzle (row&7)<<4).
// W fragments streamed from L2 with a double-buffered register prefetch
// (static indices only). Partial gate sums reduced through glds[2] in phase 3.
template <int NKC, int KCL, int KX, bool L0>
__global__ __launch_bounds__(512, 2) void lstm_layer_v4(
    const float* __restrict__ X,      // only for L0
    u16* __restrict__ seq,            // [NBLK][T][16][256] fp16, in-place x->h
    const u16* __restrict__ wf,       // this layer's packed weights
    const float* __restrict__ bias)   // [1024]
{
  __shared__ __align__(16) u16  Ahi[16 * 512];        // 16 KiB (rows at 1024 B stride)
  __shared__ float glds[2][4][16][260];               // 2 x 65 KiB partial-sum buffers

  const int tid  = threadIdx.x;
  const int wid  = tid >> 6;           // 0..7
  const int w    = wid & 3;            // gate
  const int kh   = wid >> 2;           // K-half
  const int lane = tid & 63;
  const int bid  = blockIdx.x;
  const int arow = lane & 15;          // A row / D col within MFMA
  const int ahi  = lane >> 4;          // k-group / D row-group
  const int aswz = (arow & 7) << 4;
  const int kc0  = kh * KCL;

  // zero h-part of A rows (512 B per row starting at byte KX*2)
  {
    int r = tid >> 5, o = (tid & 31) * 16;
    uint4 z; z.x = z.y = z.z = z.w = 0;
    *(uint4*)((char*)Ahi + r * 1024 + KX * 2 + o) = z;
  }

  // phase-3 state: thread owns col j = tid&255, rows rh*8..rh*8+7
  const int j  = tid & 255;
  const int rh = tid >> 8;
  float c[8];
#pragma unroll
  for (int q = 0; q < 8; ++q) c[q] = 0.f;

  float bv[16];
  if (kh == 0) {
#pragma unroll
    for (int nt = 0; nt < 16; ++nt) bv[nt] = bias[w * 256 + nt * 16 + arow];
  }

  // W base for this wave: fragment (gnt = w*16+nt, kc = kc0+i) at
  // wf[((gnt*NKC + kc)*64 + lane)*8]
  const u16* wb = wf + ((size_t)(w * 16) * NKC + kc0) * 512 + (size_t)lane * 8;

  for (int t = 0; t < T_; ++t) {
    // ---- phase 1: load x_t into A (swizzled) ----
    if constexpr (L0) {
      if (tid < 256) {
        int r = tid >> 4, seg = tid & 15;
        const float4 xv = *(const float4*)(X + ((size_t)(bid * 16 + r) * T_ + t) * D_ + seg * 4);
        uint2 pk;
        pk.x = (u32)f2h(xv.x) | ((u32)f2h(xv.y) << 16);
        pk.y = (u32)f2h(xv.z) | ((u32)f2h(xv.w) << 16);
        *(uint2*)((char*)Ahi + r * 1024 + ((seg * 8) ^ ((r & 7) << 4))) = pk;
      }
    } else {
      int r = tid >> 5, seg = tid & 31;
      uint4 v = *(const uint4*)(seq + ((((size_t)bid * T_ + t) * 16 + r) << 8) + seg * 8);
      *(uint4*)((char*)Ahi + r * 1024 + ((seg * 16) ^ ((r & 7) << 4))) = v;
    }
    __syncthreads();

    // ---- phase 2: partial gates = A[:, kc0..kc0+KCL) @ W^T (+bias for kh=0) ----
    v8hf a[KCL];
#pragma unroll
    for (int i = 0; i < KCL; ++i)
      a[i] = *(const v8hf*)((const char*)Ahi + arow * 1024 + (((kc0 + i) * 64 + ahi * 16) ^ aswz));

    // double-buffered W prefetch; all indices compile-time (full unroll)
    v8hf bf0[KCL], bf1[KCL];
#pragma unroll
    for (int i = 0; i < KCL; ++i)
      bf0[i] = *(const v8hf*)(const void*)(wb + (size_t)(0 * NKC + i) * 512);

#pragma unroll
    for (int nt = 0; nt < 16; ++nt) {
      // issue next tile's loads first
      if (nt < 15) {
        if ((nt & 1) == 0) {
#pragma unroll
          for (int i = 0; i < KCL; ++i)
            bf1[i] = *(const v8hf*)(const void*)(wb + (size_t)((nt + 1) * NKC + i) * 512);
        } else {
#pragma unroll
          for (int i = 0; i < KCL; ++i)
            bf0[i] = *(const v8hf*)(const void*)(wb + (size_t)((nt + 1) * NKC + i) * 512);
        }
      }
      f32x4 acc;
      if (kh == 0) { acc[0] = bv[nt]; acc[1] = bv[nt]; acc[2] = bv[nt]; acc[3] = bv[nt]; }
      else         { acc[0] = 0.f;    acc[1] = 0.f;    acc[2] = 0.f;    acc[3] = 0.f;    }
      if ((nt & 1) == 0) {
#pragma unroll
        for (int i = 0; i < KCL; ++i)
          acc = __builtin_amdgcn_mfma_f32_16x16x32_f16(a[i], bf0[i], acc, 0, 0, 0);
      } else {
#pragma unroll
        for (int i = 0; i < KCL; ++i)
          acc = __builtin_amdgcn_mfma_f32_16x16x32_f16(a[i], bf1[i], acc, 0, 0, 0);
      }
#pragma unroll
      for (int q = 0; q < 4; ++q)
        glds[kh][w][ahi * 4 + q][nt * 16 + arow] = acc[q];  // D: row=(lane>>4)*4+q, col=lane&15
    }
    __syncthreads();

    // ---- phase 3: reduce K-halves + nonlinearity + state update ----
    u16* srow = seq + ((((size_t)bid * T_ + t) * 16) << 8) + j;
#pragma unroll
    for (int q = 0; q < 8; ++q) {
      int r = rh * 8 + q;
      float iv = glds[0][0][r][j] + glds[1][0][r][j];
      float fv = glds[0][1][r][j] + glds[1][1][r][j];
      float gv = glds[0][2][r][j] + glds[1][2][r][j];
      float ov = glds[0][3][r][j] + glds[1][3][r][j];
      float cn = fsig(fv) * c[q] + fsig(iv) * ftanh(gv);
      c[q] = cn;
      float h = fsig(ov) * ftanh(cn);
      u16 hb = f2h(h);
      srow[(size_t)r << 8] = hb;                             // global (next layer / tail)
      *(u16*)((char*)Ahi + r * 1024 + (((KX + j) * 2) ^ ((r & 7) << 4))) = hb;  // A h-part
    }
    // next phase-1 writes the x-part (disjoint from h-part); the barrier after
    // phase 1 orders phase-3 LDS/global effects before phase 2 of t+1.
  }
}

// ---------------- tail (encoder / sample / decoder) ----------------
template <int N, int K, bool RELU>
__device__ __forceinline__ void dense(const float (*__restrict__ in)[512],
                                      float (*__restrict__ out)[512],
                                      const float* __restrict__ W,
                                      const float* __restrict__ bg, int tid) {
  for (int e = tid; e < 16 * N; e += 256) {
    int r = e / N, n = e - r * N;
    const float* wr = W + (size_t)n * K;
    const float* ar = in[r];
    float4 acc = {0.f, 0.f, 0.f, 0.f};
    for (int k = 0; k < K; k += 4) {
      float4 wv = *(const float4*)(wr + k);
      float4 av = *(const float4*)(ar + k);
      acc.x = fmaf(wv.x, av.x, acc.x);
      acc.y = fmaf(wv.y, av.y, acc.y);
      acc.z = fmaf(wv.z, av.z, acc.z);
      acc.w = fmaf(wv.w, av.w, acc.w);
    }
    float s = bg[n] + acc.x + acc.y + acc.z + acc.w;
    out[r][n] = RELU ? fmaxf(s, 0.f) : s;
  }
}

template <int K>
__device__ __forceinline__ float dotK(const float* __restrict__ a, const float* __restrict__ w) {
  float4 acc = {0.f, 0.f, 0.f, 0.f};
#pragma unroll
  for (int k = 0; k < K; k += 4) {
    float4 wv = *(const float4*)(w + k);
    float4 av = *(const float4*)(a + k);
    acc.x = fmaf(wv.x, av.x, acc.x);
    acc.y = fmaf(wv.y, av.y, acc.y);
    acc.z = fmaf(wv.z, av.z, acc.z);
    acc.w = fmaf(wv.w, av.w, acc.w);
  }
  return acc.x + acc.y + acc.z + acc.w;
}

struct TailArgs {
  const u16* seq;
  const float *ef1w, *ef1b, *ef2w, *ef2b;
  const float *mean_w, *mean_b, *logvar_w, *logvar_b;
  const float *scale_w, *scale_b, *shape_w, *shape_b;
  const float *df1w, *df1b, *df2w, *df2b, *outw, *outb, *finw, *finb;
  const float *pi, *eps, *u, *choice;
  float* out;
};

__global__ __launch_bounds__(256) void tail_kernel_v4(TailArgs A) {
  __shared__ float a0[16][512];
  __shared__ float a1[16][512];
  const int tid = threadIdx.x, bid = blockIdx.x;

  // last hidden state (t = T-1) of final layer
  for (int e = tid; e < 16 * 256; e += 256) {
    int r = e >> 8, jj = e & 255;
    a0[r][jj] = h2f(A.seq[((((size_t)bid * T_ + (T_ - 1)) * 16 + r) << 8) + jj]);
  }
  __syncthreads();

  dense<128, 256, true>(a0, a1, A.ef1w, A.ef1b, tid); __syncthreads();
  dense<64, 128, true>(a1, a0, A.ef2w, A.ef2b, tid);  __syncthreads();

  // heads + reparameterization / GPD mixture
  const float pi = *A.pi;
  for (int e = tid; e < 16 * 64; e += 256) {
    int r = e >> 6, n = e & 63;
    size_t rg = (size_t)bid * 16 + r;
    float m  = dotK<64>(a0[r], A.mean_w   + n * 64) + A.mean_b[n];
    float lv = dotK<64>(a0[r], A.logvar_w + n * 64) + A.logvar_b[n];
    float sc = __expf(dotK<64>(a0[r], A.scale_w + n * 64) + A.scale_b[n]);
    float sh = dotK<64>(a0[r], A.shape_w + n * 64) + A.shape_b[n];
    A.out[196608 + rg * 64 + n] = m;    // z_mean
    A.out[327680 + rg * 64 + n] = lv;   // z_logvar
    A.out[458752 + rg * 64 + n] = sc;   // z_scale
    A.out[589824 + rg * 64 + n] = sh;   // z_shape
    float zg = m + A.eps[rg * 64 + n] * __expf(0.5f * lv);
    float L  = log1pf(-A.u[rg * 64 + n]);
    float zp = sc / sh * (__expf(-sh * L) - 1.f);
    a1[r][n] = (A.choice[rg] < pi) ? zg : zp;
  }
  __syncthreads();

  dense<128, 64, true>(a1, a0, A.df1w, A.df1b, tid);   __syncthreads();
  dense<500, 128, true>(a0, a1, A.df2w, A.df2b, tid);  __syncthreads();
  dense<96, 500, false>(a1, a0, A.outw, A.outb, tid);  __syncthreads();
  dense<96, 96, false>(a0, a1, A.finw, A.finb, tid);   __syncthreads();

  for (int e = tid; e < 16 * FUT_; e += 256) {
    int r = e / FUT_, n = e - r * FUT_;
    A.out[((size_t)bid * 16 + r) * FUT_ + n] = a1[r][n];
  }
}

// ---------------- launch ----------------
extern "C" void kernel_launch(void* const* d_in, const int* in_sizes, int n_in,
                              void* d_out, int out_size, void* d_ws, size_t ws_size,
                              hipStream_t stream) {
  (void)in_sizes; (void)n_in; (void)out_size; (void)ws_size;

  const float* X      = (const float*)d_in[0];
  const float* Wih0   = (const float*)d_in[1];
  const float* Wih    = (const float*)d_in[2];
  const float* Whh    = (const float*)d_in[3];
  const float* b      = (const float*)d_in[4];
  const float* ef1w   = (const float*)d_in[5];
  const float* ef1b   = (const float*)d_in[6];
  const float* ef2w   = (const float*)d_in[7];
  const float* ef2b   = (const float*)d_in[8];
  const float* mean_w = (const float*)d_in[9];
  const float* mean_b = (const float*)d_in[10];
  const float* logvar_w = (const float*)d_in[11];
  const float* logvar_b = (const float*)d_in[12];
  const float* scale_w  = (const float*)d_in[13];
  const float* scale_b  = (const float*)d_in[14];
  const float* shape_w  = (const float*)d_in[15];
  const float* shape_b  = (const float*)d_in[16];
  const float* df1w   = (const float*)d_in[17];
  const float* df1b   = (const float*)d_in[18];
  const float* df2w   = (const float*)d_in[19];
  const float* df2b   = (const float*)d_in[20];
  const float* outw   = (const float*)d_in[21];
  const float* outb   = (const float*)d_in[22];
  const float* finw   = (const float*)d_in[23];
  const float* finb   = (const float*)d_in[24];
  const float* pi_g   = (const float*)d_in[25];
  const float* eps    = (const float*)d_in[26];
  const float* u      = (const float*)d_in[27];
  const float* choice = (const float*)d_in[28];

  u16* wf  = (u16*)d_ws;
  u16* seq = (u16*)((char*)d_ws + SEQ_OFF);
  float* out = (float*)d_out;

  pack_weights_v4<<<2560, 256, 0, stream>>>(Wih0, Wih, Whh, wf);

  // LSTM stack (in-place on seq; layer 0 reads X)
  lstm_layer_v4<10, 5, 64, true><<<NBLK, 512, 0, stream>>>(X, seq, wf, b);
  for (int l = 1; l < NL_; ++l)
    lstm_layer_v4<16, 8, 256, false><<<NBLK, 512, 0, stream>>>(nullptr, seq,
        wf + (size_t)l * WF_LAYER_ELEMS, b + l * 1024);

  TailArgs A;
  A.seq = seq;
  A.ef1w = ef1w; A.ef1b = ef1b; A.ef2w = ef2w; A.ef2b = ef2b;
  A.mean_w = mean_w; A.mean_b = mean_b; A.logvar_w = logvar_w; A.logvar_b = logvar_b;
  A.scale_w = scale_w; A.scale_b = scale_b; A.shape_w = shape_w; A.shape_b = shape_b;
  A.df1w = df1w; A.df1b = df1b; A.df2w = df2w; A.df2b = df2b;
  A.outw = outw; A.outb = outb; A.finw = finw; A.finb = finb;
  A.pi = pi_g; A.eps = eps; A.u = u; A.choice = choice;
  A.out = out;
  tail_kernel_v4<<<NBLK, 512 / 2, 0, stream>>>(A);
}

// Round 5
// 23708.435 us; speedup vs baseline: 1.0939x; 1.0046x over previous
//
#include <hip/hip_runtime.h>

typedef unsigned short u16;
typedef unsigned int   u32;
typedef _Float16 v8hf __attribute__((ext_vector_type(8)));
typedef float  f32x4 __attribute__((ext_vector_type(4)));

// ---------------- problem constants ----------------
static constexpr int B_   = 2048;
static constexpr int T_   = 64;
static constexpr int D_   = 64;
static constexpr int H_   = 256;
static constexpr int NL_  = 10;
static constexpr int FUT_ = 96;
static constexpr int NBLK = 128;     // B/16

// workspace layout (bytes)
static constexpr size_t WF_LAYER_ELEMS = 524288;          // u16 per layer (1 MiB)
static constexpr size_t SEQ_OFF        = 16u << 20;       // seq buffer at +16 MiB
// seq: fp16 [NBLK][T][16][256]  = 64 MiB

// ---------------- small helpers ----------------
__device__ __forceinline__ u16 f2h(float f) {
  _Float16 h = (_Float16)f;                 // RNE v_cvt_f16_f32
  return __builtin_bit_cast(u16, h);
}
__device__ __forceinline__ float h2f(u16 b) {
  return (float)__builtin_bit_cast(_Float16, b);
}
__device__ __forceinline__ float rcp_(float x) { return __builtin_amdgcn_rcpf(x); }
__device__ __forceinline__ float fsig(float x) { return rcp_(1.f + __expf(-x)); }
__device__ __forceinline__ float ftanh(float x) {
  float e = __expf(-2.f * fabsf(x));
  float t = (1.f - e) * rcp_(1.f + e);
  return copysignf(t, x);
}

// ---------------- weight packing (fp16 B-fragment order) ----------------
// Fragment (gnt, kc): element (lane, i) = Wcat[g = gnt*16 + (lane&15)][k = kc*32 + (lane>>4)*8 + i]
__global__ void pack_weights_v4(const float* __restrict__ Wih0,
                                const float* __restrict__ Wih,
                                const float* __restrict__ Whh,
                                u16* __restrict__ wf) {
  int gid = blockIdx.x * 256 + threadIdx.x;
  int l   = gid >> 16;            // 65536 frag-threads per layer
  if (l >= NL_) return;
  int rem  = gid & 65535;
  int gnt  = rem >> 10;           // 0..63
  int kc   = (rem >> 6) & 15;     // 0..15
  int lane = rem & 63;
  const int NKC = (l == 0) ? 10 : 16;
  if (kc >= NKC) return;
  const int KX = (l == 0) ? 64 : 256;

  int g  = gnt * 16 + (lane & 15);
  int k0 = kc * 32 + (lane >> 4) * 8;

  float v[8];
#pragma unroll
  for (int i = 0; i < 8; ++i) {
    int k = k0 + i;
    float x;
    if (l == 0) x = (k < KX) ? Wih0[g * 64 + k] : Whh[g * 256 + (k - KX)];
    else        x = (k < KX) ? Wih[(size_t)((l - 1) * 1024 + g) * 256 + k]
                             : Whh[(size_t)(l * 1024 + g) * 256 + (k - KX)];
    v[i] = x;
  }
  u32 pk[4];
#pragma unroll
  for (int i = 0; i < 4; ++i)
    pk[i] = (u32)f2h(v[2 * i]) | ((u32)f2h(v[2 * i + 1]) << 16);
  uint4 val; val.x = pk[0]; val.y = pk[1]; val.z = pk[2]; val.w = pk[3];
  u16* dst = wf + (size_t)l * WF_LAYER_ELEMS + ((size_t)(gnt * NKC + kc) * 64 + lane) * 8;
  *(uint4*)dst = val;
}

// ---------------- LSTM layer v4 ----------------
// One block = 16 batch rows, 512 threads = 8 waves = 4 gates x 2 K-halves.
// Wave (w, kh): gate w (cols w*256..), kc in [kh*KCL, (kh+1)*KCL).
// A = [x_t ; h_{t-1}] 16 x K fp16 in LDS (row stride 1024B fixed, XOR swizzle (row&7)<<4).
// W fragments streamed from L2 with a double-buffered register prefetch
// (static indices only). Partial gate sums reduced through glds[2] in phase 3.
template <int NKC, int KCL, int KX, bool L0>
__global__ __launch_bounds__(512, 2) void lstm_layer_v4(
    const float* __restrict__ X,      // only for L0
    u16* __restrict__ seq,            // [NBLK][T][16][256] fp16, in-place x->h
    const u16* __restrict__ wf,       // this layer's packed weights
    const float* __restrict__ bias)   // [1024]
{
  __shared__ __align__(16) u16  Ahi[16 * 512];        // 16 KiB (rows at 1024 B stride)
  __shared__ float glds[2][4][16][260];               // 2 x 65 KiB partial-sum buffers

  const int tid  = threadIdx.x;
  const int wid  = tid >> 6;           // 0..7
  const int w    = wid & 3;            // gate
  const int kh   = wid >> 2;           // K-half
  const int lane = tid & 63;
  const int bid  = blockIdx.x;
  const int arow = lane & 15;          // A row / D col within MFMA
  const int ahi  = lane >> 4;          // k-group / D row-group
  const int aswz = (arow & 7) << 4;
  const int kc0  = kh * KCL;

  // zero h-part of A rows (512 B per row starting at byte KX*2)
  {
    int r = tid >> 5, o = (tid & 31) * 16;
    uint4 z; z.x = z.y = z.z = z.w = 0;
    *(uint4*)((char*)Ahi + r * 1024 + KX * 2 + o) = z;
  }

  // phase-3 state: thread owns col j = tid&255, rows rh*8..rh*8+7
  const int j  = tid & 255;
  const int rh = tid >> 8;
  float c[8];
#pragma unroll
  for (int q = 0; q < 8; ++q) c[q] = 0.f;

  float bv[16];
  if (kh == 0) {
#pragma unroll
    for (int nt = 0; nt < 16; ++nt) bv[nt] = bias[w * 256 + nt * 16 + arow];
  }

  // W base for this wave: fragment (gnt = w*16+nt, kc = kc0+i) at
  // wf[((gnt*NKC + kc)*64 + lane)*8]
  const u16* wb = wf + ((size_t)(w * 16) * NKC + kc0) * 512 + (size_t)lane * 8;

  for (int t = 0; t < T_; ++t) {
    // ---- phase 1: load x_t into A (swizzled) ----
    if constexpr (L0) {
      if (tid < 256) {
        int r = tid >> 4, seg = tid & 15;
        const float4 xv = *(const float4*)(X + ((size_t)(bid * 16 + r) * T_ + t) * D_ + seg * 4);
        uint2 pk;
        pk.x = (u32)f2h(xv.x) | ((u32)f2h(xv.y) << 16);
        pk.y = (u32)f2h(xv.z) | ((u32)f2h(xv.w) << 16);
        *(uint2*)((char*)Ahi + r * 1024 + ((seg * 8) ^ ((r & 7) << 4))) = pk;
      }
    } else {
      int r = tid >> 5, seg = tid & 31;
      uint4 v = *(const uint4*)(seq + ((((size_t)bid * T_ + t) * 16 + r) << 8) + seg * 8);
      *(uint4*)((char*)Ahi + r * 1024 + ((seg * 16) ^ ((r & 7) << 4))) = v;
    }
    __syncthreads();

    // ---- phase 2: partial gates = A[:, kc0..kc0+KCL) @ W^T (+bias for kh=0) ----
    v8hf a[KCL];
#pragma unroll
    for (int i = 0; i < KCL; ++i)
      a[i] = *(const v8hf*)((const char*)Ahi + arow * 1024 + (((kc0 + i) * 64 + ahi * 16) ^ aswz));

    // double-buffered W prefetch; all indices compile-time (full unroll)
    v8hf bf0[KCL], bf1[KCL];
#pragma unroll
    for (int i = 0; i < KCL; ++i)
      bf0[i] = *(const v8hf*)(const void*)(wb + (size_t)(0 * NKC + i) * 512);

#pragma unroll
    for (int nt = 0; nt < 16; ++nt) {
      // issue next tile's loads first
      if (nt < 15) {
        if ((nt & 1) == 0) {
#pragma unroll
          for (int i = 0; i < KCL; ++i)
            bf1[i] = *(const v8hf*)(const void*)(wb + (size_t)((nt + 1) * NKC + i) * 512);
        } else {
#pragma unroll
          for (int i = 0; i < KCL; ++i)
            bf0[i] = *(const v8hf*)(const void*)(wb + (size_t)((nt + 1) * NKC + i) * 512);
        }
      }
      f32x4 acc;
      if (kh == 0) { acc[0] = bv[nt]; acc[1] = bv[nt]; acc[2] = bv[nt]; acc[3] = bv[nt]; }
      else         { acc[0] = 0.f;    acc[1] = 0.f;    acc[2] = 0.f;    acc[3] = 0.f;    }
      if ((nt & 1) == 0) {
#pragma unroll
        for (int i = 0; i < KCL; ++i)
          acc = __builtin_amdgcn_mfma_f32_16x16x32_f16(a[i], bf0[i], acc, 0, 0, 0);
      } else {
#pragma unroll
        for (int i = 0; i < KCL; ++i)
          acc = __builtin_amdgcn_mfma_f32_16x16x32_f16(a[i], bf1[i], acc, 0, 0, 0);
      }
#pragma unroll
      for (int q = 0; q < 4; ++q)
        glds[kh][w][ahi * 4 + q][nt * 16 + arow] = acc[q];  // D: row=(lane>>4)*4+q, col=lane&15
    }
    __syncthreads();

    // ---- phase 3: reduce K-halves + nonlinearity + state update ----
    u16* srow = seq + ((((size_t)bid * T_ + t) * 16) << 8) + j;
#pragma unroll
    for (int q = 0; q < 8; ++q) {
      int r = rh * 8 + q;
      float iv = glds[0][0][r][j] + glds[1][0][r][j];
      float fv = glds[0][1][r][j] + glds[1][1][r][j];
      float gv = glds[0][2][r][j] + glds[1][2][r][j];
      float ov = glds[0][3][r][j] + glds[1][3][r][j];
      float cn = fsig(fv) * c[q] + fsig(iv) * ftanh(gv);
      c[q] = cn;
      float h = fsig(ov) * ftanh(cn);
      u16 hb = f2h(h);
      srow[(size_t)r << 8] = hb;                             // global (next layer / tail)
      *(u16*)((char*)Ahi + r * 1024 + (((KX + j) * 2) ^ ((r & 7) << 4))) = hb;  // A h-part
    }
    // next phase-1 writes the x-part (disjoint from h-part); the barrier after
    // phase 1 orders phase-3 LDS/global effects before phase 2 of t+1.
  }
}

// ---------------- tail (encoder / sample / decoder) ----------------
template <int N, int K, bool RELU>
__device__ __forceinline__ void dense(const float (*__restrict__ in)[512],
                                      float (*__restrict__ out)[512],
                                      const float* __restrict__ W,
                                      const float* __restrict__ bg, int tid) {
  for (int e = tid; e < 16 * N; e += 256) {
    int r = e / N, n = e - r * N;
    const float* wr = W + (size_t)n * K;
    const float* ar = in[r];
    float4 acc = {0.f, 0.f, 0.f, 0.f};
    for (int k = 0; k < K; k += 4) {
      float4 wv = *(const float4*)(wr + k);
      float4 av = *(const float4*)(ar + k);
      acc.x = fmaf(wv.x, av.x, acc.x);
      acc.y = fmaf(wv.y, av.y, acc.y);
      acc.z = fmaf(wv.z, av.z, acc.z);
      acc.w = fmaf(wv.w, av.w, acc.w);
    }
    float s = bg[n] + acc.x + acc.y + acc.z + acc.w;
    out[r][n] = RELU ? fmaxf(s, 0.f) : s;
  }
}

template <int K>
__device__ __forceinline__ float dotK(const float* __restrict__ a, const float* __restrict__ w) {
  float4 acc = {0.f, 0.f, 0.f, 0.f};
#pragma unroll
  for (int k = 0; k < K; k += 4) {
    float4 wv = *(const float4*)(w + k);
    float4 av = *(const float4*)(a + k);
    acc.x = fmaf(wv.x, av.x, acc.x);
    acc.y = fmaf(wv.y, av.y, acc.y);
    acc.z = fmaf(wv.z, av.z, acc.z);
    acc.w = fmaf(wv.w, av.w, acc.w);
  }
  return acc.x + acc.y + acc.z + acc.w;
}

struct TailArgs {
  const u16* seq;
  const float *ef1w, *ef1b, *ef2w, *ef2b;
  const float *mean_w, *mean_b, *logvar_w, *logvar_b;
  const float *scale_w, *scale_b, *shape_w, *shape_b;
  const float *df1w, *df1b, *df2w, *df2b, *outw, *outb, *finw, *finb;
  const float *pi, *eps, *u, *choice;
  float* out;
};

__global__ __launch_bounds__(256) void tail_kernel_v4(TailArgs A) {
  __shared__ float a0[16][512];
  __shared__ float a1[16][512];
  const int tid = threadIdx.x, bid = blockIdx.x;

  // last hidden state (t = T-1) of final layer
  for (int e = tid; e < 16 * 256; e += 256) {
    int r = e >> 8, jj = e & 255;
    a0[r][jj] = h2f(A.seq[((((size_t)bid * T_ + (T_ - 1)) * 16 + r) << 8) + jj]);
  }
  __syncthreads();

  dense<128, 256, true>(a0, a1, A.ef1w, A.ef1b, tid); __syncthreads();
  dense<64, 128, true>(a1, a0, A.ef2w, A.ef2b, tid);  __syncthreads();

  // heads + reparameterization / GPD mixture
  const float pi = *A.pi;
  for (int e = tid; e < 16 * 64; e += 256) {
    int r = e >> 6, n = e & 63;
    size_t rg = (size_t)bid * 16 + r;
    float m  = dotK<64>(a0[r], A.mean_w   + n * 64) + A.mean_b[n];
    float lv = dotK<64>(a0[r], A.logvar_w + n * 64) + A.logvar_b[n];
    float sc = __expf(dotK<64>(a0[r], A.scale_w + n * 64) + A.scale_b[n]);
    float sh = dotK<64>(a0[r], A.shape_w + n * 64) + A.shape_b[n];
    A.out[196608 + rg * 64 + n] = m;    // z_mean
    A.out[327680 + rg * 64 + n] = lv;   // z_logvar
    A.out[458752 + rg * 64 + n] = sc;   // z_scale
    A.out[589824 + rg * 64 + n] = sh;   // z_shape
    float zg = m + A.eps[rg * 64 + n] * __expf(0.5f * lv);
    float L  = log1pf(-A.u[rg * 64 + n]);
    float zp = sc / sh * (__expf(-sh * L) - 1.f);
    a1[r][n] = (A.choice[rg] < pi) ? zg : zp;
  }
  __syncthreads();

  dense<128, 64, true>(a1, a0, A.df1w, A.df1b, tid);   __syncthreads();
  dense<500, 128, true>(a0, a1, A.df2w, A.df2b, tid);  __syncthreads();
  dense<96, 500, false>(a1, a0, A.outw, A.outb, tid);  __syncthreads();
  dense<96, 96, false>(a0, a1, A.finw, A.finb, tid);   __syncthreads();

  for (int e = tid; e < 16 * FUT_; e += 256) {
    int r = e / FUT_, n = e - r * FUT_;
    A.out[((size_t)bid * 16 + r) * FUT_ + n] = a1[r][n];
  }
}

// ---------------- launch ----------------
extern "C" void kernel_launch(void* const* d_in, const int* in_sizes, int n_in,
                              void* d_out, int out_size, void* d_ws, size_t ws_size,
                              hipStream_t stream) {
  (void)in_sizes; (void)n_in; (void)out_size; (void)ws_size;

  const float* X      = (const float*)d_in[0];
  const float* Wih0   = (const float*)d_in[1];
  const float* Wih    = (const float*)d_in[2];
  const float* Whh    = (const float*)d_in[3];
  const float* b      = (const float*)d_in[4];
  const float* ef1w   = (const float*)d_in[5];
  const float* ef1b   = (const float*)d_in[6];
  const float* ef2w   = (const float*)d_in[7];
  const float* ef2b   = (const float*)d_in[8];
  const float* mean_w = (const float*)d_in[9];
  const float* mean_b = (const float*)d_in[10];
  const float* logvar_w = (const float*)d_in[11];
  const float* logvar_b = (const float*)d_in[12];
  const float* scale_w  = (const float*)d_in[13];
  const float* scale_b  = (const float*)d_in[14];
  const float* shape_w  = (const float*)d_in[15];
  const float* shape_b  = (const float*)d_in[16];
  const float* df1w   = (const float*)d_in[17];
  const float* df1b   = (const float*)d_in[18];
  const float* df2w   = (const float*)d_in[19];
  const float* df2b   = (const float*)d_in[20];
  const float* outw   = (const float*)d_in[21];
  const float* outb   = (const float*)d_in[22];
  const float* finw   = (const float*)d_in[23];
  const float* finb   = (const float*)d_in[24];
  const float* pi_g   = (const float*)d_in[25];
  const float* eps    = (const float*)d_in[26];
  const float* u      = (const float*)d_in[27];
  const float* choice = (const float*)d_in[28];

  u16* wf  = (u16*)d_ws;
  u16* seq = (u16*)((char*)d_ws + SEQ_OFF);
  float* out = (float*)d_out;

  pack_weights_v4<<<2560, 256, 0, stream>>>(Wih0, Wih, Whh, wf);

  // LSTM stack (in-place on seq; layer 0 reads X)
  lstm_layer_v4<10, 5, 64, true><<<NBLK, 512, 0, stream>>>(X, seq, wf, b);
  for (int l = 1; l < NL_; ++l)
    lstm_layer_v4<16, 8, 256, false><<<NBLK, 512, 0, stream>>>(nullptr, seq,
        wf + (size_t)l * WF_LAYER_ELEMS, b + l * 1024);

  TailArgs A;
  A.seq = seq;
  A.ef1w = ef1w; A.ef1b = ef1b; A.ef2w = ef2w; A.ef2b = ef2b;
  A.mean_w = mean_w; A.mean_b = mean_b; A.logvar_w = logvar_w; A.logvar_b = logvar_b;
  A.scale_w = scale_w; A.scale_b = scale_b; A.shape_w = shape_w; A.shape_b = shape_b;
  A.df1w = df1w; A.df1b = df1b; A.df2w = df2w; A.df2b = df2b;
  A.outw = outw; A.outb = outb; A.finw = finw; A.finb = finb;
  A.pi = pi_g; A.eps = eps; A.u = u; A.choice = choice;
  A.out = out;
  tail_kernel_v4<<<NBLK, 512 / 2, 0, stream>>>(A);
}